// Round 6
// baseline (183.279 us; speedup 1.0000x reference)
//
#include <hip/hip_runtime.h>
#include <math.h>

// Problem constants
#define KJ 24
#define NV 6890
#define PREG 200
#define M_TOT (NV*3)          // 20670
#define KDIM 391              // 23*17
#define KPAD 416              // 13 chunks of 32
#define TP_STRIDE 20672       // TP row stride (2 pad cols)
#define NMT64 323             // 64-wide m-tiles (kStage AND kB)
#define NSTAGE (NMT64*13)     // 4199 stage blocks

// Workspace layout (float offsets unless _U = ushort offsets). ~78 MB total.
#define EDP_OFF 0               // 675 E_D partials (kC 27 x 25)
#define EKP_OFF 5400            // 23*4199 = 96,577 E_K partials (kStage)
#define WIP_OFF 101984          // 27 E_Wi partials
#define EWP_OFF 102016          // 27 E_W partials
#define EAP_OFF 102048          // 27 E_A partials
#define RED_OFF 102080          // 32 final partials
#define G_OFF   102112          // G' : 200 x 24 x 12
#define TP_OFF  159712          // T_p 256 x 20672 (p-major), K-half 0
#define QBH_OFF_U 10903488      // qm hi bf16, 256 x 416
#define QBL_OFF_U 11009984      // qm lo bf16, 256 x 416
#define BTH_OFF_U 11116480      // Bt hi bf16, 20672 x 416 (m-major)
#define BTL_OFF_U 19716032      // Bt lo bf16, 20672 x 416
#define TP2_OFF 14157792        // T_p partial, K-half 1

typedef __attribute__((ext_vector_type(8))) short short8;
typedef __attribute__((ext_vector_type(4))) float f32x4;
typedef __attribute__((ext_vector_type(4))) unsigned int u32x4;

__constant__ int c_PARENT[24] = {0,0,0,0,1,2,3,4,5,6,7,8,9,9,9,12,13,14,16,17,18,19,20,21};
__constant__ int c_DEPTH[24]  = {0,1,1,1,2,2,2,3,3,3,4,4,4,4,4,5,5,5,6,6,7,7,8,8};
__constant__ int c_LEN[24]    = {4,3,3,3,3,3,3,3,3,2,2,2,4,3,3,2,3,3,3,3,3,3,2,2};
__constant__ int c_NBR[24][4] = {
  {0,1,2,3},{0,1,4,0},{0,2,5,0},{0,3,6,0},{1,4,7,0},{2,5,8,0},{3,6,9,0},{4,7,10,0},
  {5,8,11,0},{6,9,0,0},{7,10,0,0},{8,11,0,0},{12,13,14,15},{12,13,16,0},{12,14,17,0},
  {12,15,0,0},{13,16,18,0},{14,17,19,0},{16,18,20,0},{17,19,21,0},{18,20,22,0},
  {19,21,23,0},{20,22,0,0},{21,23,0,0}};

__device__ __forceinline__ float waveReduce(float v) {
  #pragma unroll
  for (int off = 32; off > 0; off >>= 1) v += __shfl_down(v, off, 64);
  return v;
}
__device__ __forceinline__ unsigned short f2bf(float x) {
  union { float f; unsigned u; } v; v.f = x;
  unsigned r = v.u + 0x7FFFu + ((v.u >> 16) & 1u);
  return (unsigned short)(r >> 16);
}
__device__ __forceinline__ float bf2f(unsigned short h) {
  union { unsigned u; float f; } v; v.u = ((unsigned)h) << 16; return v.f;
}

// ---- kPre: b<50: pose math (4 p/block) -> G' + qm bf16 hi/lo planes
//            b<77: E_Wi/E_W/E_A partials + qm pad-row zeroing
//            else: kStage — Bt[m][k] = bf16-split(K ⊙ reluA) transpose + E_K ----
__global__ __launch_bounds__(256) void kPre(const float* __restrict__ J,
                                            const float* __restrict__ theta,
                                            const float* __restrict__ beta2,
                                            const float* __restrict__ Wp,
                                            const float* __restrict__ Wi,
                                            const float* __restrict__ A,
                                            const float* __restrict__ K,
                                            float* __restrict__ ws) {
  unsigned short* qbh = (unsigned short*)ws + QBH_OFF_U;
  unsigned short* qbl = (unsigned short*)ws + QBL_OFF_U;
  int b = blockIdx.x;
  if (b < 50) {
    __shared__ float Gl[4][24][12];
    __shared__ float Gg[4][24][12];
    __shared__ float q[4][24][4];
    int w = threadIdx.x >> 6, t = threadIdx.x & 63;
    int p = b*4 + w;
    if (t < 24) {
      float x = theta[p*72 + 3*t + 0];
      float y = theta[p*72 + 3*t + 1];
      float z = theta[p*72 + 3*t + 2];
      float n2 = x*x + y*y + z*z;
      float ang = fmaxf(sqrtf(n2), 1e-8f);
      float ia = 1.f/ang;
      float ax = x*ia, ay = y*ia, az = z*ia;
      float c = cosf(ang), s = sinf(ang), C = 1.f - c;
      float jx = J[p*72+3*t], jy = J[p*72+3*t+1], jz = J[p*72+3*t+2];
      float tx = jx, ty = jy, tz = jz;
      if (t > 0) {
        int par = c_PARENT[t];
        tx -= J[p*72+3*par]; ty -= J[p*72+3*par+1]; tz -= J[p*72+3*par+2];
      }
      Gl[w][t][0]=c+C*ax*ax;   Gl[w][t][1]=C*ax*ay-s*az; Gl[w][t][2]=C*ax*az+s*ay; Gl[w][t][3]=tx;
      Gl[w][t][4]=C*ax*ay+s*az;Gl[w][t][5]=c+C*ay*ay;    Gl[w][t][6]=C*ay*az-s*ax; Gl[w][t][7]=ty;
      Gl[w][t][8]=C*ax*az-s*ay;Gl[w][t][9]=C*ay*az+s*ax; Gl[w][t][10]=c+C*az*az;   Gl[w][t][11]=tz;
      float ang2 = sqrtf(fmaxf(n2, 1e-16f));
      float inv2 = 1.f/ang2;
      float s2 = sinf(0.5f*ang2);
      q[w][t][0] = x*inv2*s2; q[w][t][1] = y*inv2*s2; q[w][t][2] = z*inv2*s2;
      q[w][t][3] = cosf(0.5f*ang2) - 1.f;
    }
    __syncthreads();
    for (int lev = 0; lev <= 8; lev++) {
      if (t < 24 && c_DEPTH[t] == lev) {
        if (lev == 0) {
          for (int i2 = 0; i2 < 12; i2++) Gg[w][0][i2] = Gl[w][0][i2];
        } else {
          int par = c_PARENT[t];
          for (int r = 0; r < 3; r++) {
            float g0 = Gg[w][par][r*4+0], g1 = Gg[w][par][r*4+1];
            float g2 = Gg[w][par][r*4+2], g3 = Gg[w][par][r*4+3];
            for (int c2 = 0; c2 < 4; c2++) {
              float v = g0*Gl[w][t][0+c2] + g1*Gl[w][t][4+c2] + g2*Gl[w][t][8+c2];
              if (c2 == 3) v += g3;
              Gg[w][t][r*4+c2] = v;
            }
          }
        }
      }
      __syncthreads();
    }
    if (t < 24) {
      float jx = J[p*72+3*t], jy = J[p*72+3*t+1], jz = J[p*72+3*t+2];
      float* gp = ws + G_OFF + p*288 + t*12;
      #pragma unroll
      for (int r = 0; r < 3; r++) {
        float off = Gg[w][t][r*4+0]*jx + Gg[w][t][r*4+1]*jy + Gg[w][t][r*4+2]*jz;
        Gg[w][t][r*4+3] -= off;
      }
      #pragma unroll
      for (int i2 = 0; i2 < 12; i2++) gp[i2] = Gg[w][t][i2];
    }
    __syncthreads();
    float b2 = beta2[0];
    for (int e = t; e < KDIM; e += 64) {
      int j = e / 17, l = e - 17*j;
      int k = j + 1;
      float val = 0.f;
      if (l < 4*c_LEN[j] + 1) {
        if (l < 16) {
          int sidx = l >> 2, cc = l & 3;
          if (sidx < c_LEN[k]) val = q[w][c_NBR[k][sidx]][cc];
        }
        if (l == 4*c_LEN[k]) val += b2;
      }
      unsigned short hi = f2bf(val);
      unsigned short lo = f2bf(val - bf2f(hi));
      qbh[p*KPAD + e] = hi;
      qbl[p*KPAD + e] = lo;
    }
    for (int e = KDIM + t; e < KPAD; e += 64) {
      qbh[p*KPAD + e] = 0; qbl[p*KPAD + e] = 0;
    }
  } else if (b < 77) {
    int d = b - 50;                        // 0..26
    int t = threadIdx.x;
    int n = d*256 + t;
    float ewi = 0.f, ew = 0.f, ea = 0.f;
    if (n < NV) {
      float wv[24]; float sum = 0.f;
      const float4* wp4 = (const float4*)(Wp + n*24);
      #pragma unroll
      for (int i = 0; i < 6; i++) {
        float4 v4 = wp4[i];
        wv[4*i+0] = fmaxf(v4.x, 0.f); wv[4*i+1] = fmaxf(v4.y, 0.f);
        wv[4*i+2] = fmaxf(v4.z, 0.f); wv[4*i+3] = fmaxf(v4.w, 0.f);
        sum += wv[4*i+0]+wv[4*i+1]+wv[4*i+2]+wv[4*i+3];
      }
      float inv = 1.f/(sum + 1e-8f);
      #pragma unroll
      for (int k = 0; k < 24; k++) {
        float wc = wv[k]*inv;
        ew += fabsf(wc);
        float dd = wc - Wi[n*24+k];
        ewi += dd*dd;
      }
    }
    for (int i = d*256 + t; i < 23*NV; i += 27*256) ea += fabsf(A[i]);
    for (int i = d*256 + t; i < 56*KPAD; i += 27*256) {
      qbh[200*KPAD + i] = 0; qbl[200*KPAD + i] = 0;
    }
    __shared__ float red[3][4];
    int lane = t & 63, wv2 = t >> 6;
    ewi = waveReduce(ewi); ew = waveReduce(ew); ea = waveReduce(ea);
    if (lane == 0) { red[0][wv2] = ewi; red[1][wv2] = ew; red[2][wv2] = ea; }
    __syncthreads();
    if (t == 0) {
      ws[WIP_OFF + d] = red[0][0]+red[0][1]+red[0][2]+red[0][3];
      ws[EWP_OFF + d] = red[1][0]+red[1][1]+red[1][2]+red[1][3];
      ws[EAP_OFF + d] = red[2][0]+red[2][1]+red[2][2]+red[2][3];
    }
  } else {
    // ---------------- kStage: 64m x 32k tile transpose ----------------
    int flat = b - 77;                     // 0..4198
    int bx = flat % NMT64, by = flat / NMT64;
    int m0 = bx*64, kg0 = by*32;
    __shared__ unsigned short Sh[32*66];   // [krow][m], stride 66 (2-way-free)
    __shared__ unsigned short Sl[32*66];
    __shared__ float ek[23];
    int t = threadIdx.x;
    if (t < 23) ek[t] = 0.f;
    __syncthreads();
    int krow = t >> 3, mseg = (t & 7) * 8;
    int kg = kg0 + krow;
    int mm = m0 + mseg;
    float kv[8], wv[8]; float sq = 0.f;
    #pragma unroll
    for (int i = 0; i < 8; i++) { kv[i] = 0.f; wv[i] = 0.f; }
    if (kg < KDIM) {
      const float* kr = K + (size_t)kg*M_TOT + mm;
      if (mm + 7 < M_TOT) {
        float4 a4 = *(const float4*)kr; float4 b4 = *(const float4*)(kr+4);
        kv[0]=a4.x; kv[1]=a4.y; kv[2]=a4.z; kv[3]=a4.w;
        kv[4]=b4.x; kv[5]=b4.y; kv[6]=b4.z; kv[7]=b4.w;
      } else {
        #pragma unroll
        for (int i = 0; i < 8; i++) if (mm+i < M_TOT) kv[i] = kr[i];
      }
      int j = kg / 17;
      // A values for m = mm..mm+7 span n0..n0+3 (4 loads + select)
      int nb = mm / 3;
      float av[4];
      #pragma unroll
      for (int i = 0; i < 4; i++)
        av[i] = (nb + i < NV) ? fmaxf(A[j*NV + nb + i], 0.f) : 0.f;
      #pragma unroll
      for (int i = 0; i < 8; i++) {
        float a = (mm+i < M_TOT) ? av[(mm+i)/3 - nb] : 0.f;
        wv[i] = kv[i]*a;
        sq = fmaf(kv[i], kv[i], sq);
      }
    }
    #pragma unroll
    for (int c = 0; c < 4; c++) {
      unsigned short h0 = f2bf(wv[2*c]),  h1 = f2bf(wv[2*c+1]);
      unsigned short l0 = f2bf(wv[2*c]   - bf2f(h0));
      unsigned short l1 = f2bf(wv[2*c+1] - bf2f(h1));
      *(unsigned*)&Sh[krow*66 + mseg + 2*c] = (unsigned)h0 | ((unsigned)h1 << 16);
      *(unsigned*)&Sl[krow*66 + mseg + 2*c] = (unsigned)l0 | ((unsigned)l1 << 16);
    }
    sq += __shfl_xor(sq, 1, 64);
    sq += __shfl_xor(sq, 2, 64);
    sq += __shfl_xor(sq, 4, 64);
    if ((t & 7) == 0 && kg < KDIM) atomicAdd(&ek[kg/17], sq);
    __syncthreads();
    int mrow = t >> 2, kq = t & 3;
    unsigned dh[4], dl[4];
    #pragma unroll
    for (int c2 = 0; c2 < 4; c2++) {
      unsigned short s0 = Sh[(kq*8 + 2*c2    )*66 + mrow];
      unsigned short s1 = Sh[(kq*8 + 2*c2 + 1)*66 + mrow];
      dh[c2] = (unsigned)s0 | ((unsigned)s1 << 16);
      unsigned short u0 = Sl[(kq*8 + 2*c2    )*66 + mrow];
      unsigned short u1 = Sl[(kq*8 + 2*c2 + 1)*66 + mrow];
      dl[c2] = (unsigned)u0 | ((unsigned)u1 << 16);
    }
    unsigned short* BtH = (unsigned short*)ws + BTH_OFF_U;
    unsigned short* BtL = (unsigned short*)ws + BTL_OFF_U;
    size_t o = (size_t)(m0 + mrow)*KPAD + kg0 + kq*8;
    *(u32x4*)(BtH + o) = (u32x4){dh[0], dh[1], dh[2], dh[3]};
    *(u32x4*)(BtL + o) = (u32x4){dl[0], dl[1], dl[2], dl[3]};
    if (t < 23) ws[EKP_OFF + t*NSTAGE + flat] = ek[t];
  }
}

// ---- kB: split-bf16 MFMA GEMM, m-tile 64, split-K x2 (grid 323 x 2),
//      256 thr. EXACT round-3 LDS mapping (stride 40 shorts): measured-best
//      kB (~28 us inferred). Round-5's "linear" relayout put write lanes
//      0-3 at bytes {0,256,512,768} = same 4 banks -> 4-way ds_write
//      conflict, +10 us. Stride-40 is <=2-way (free) on both sides for
//      this 4-wave pattern. ----
template<int KS0, int NKS>
__device__ __forceinline__ void kb_body(const unsigned short* __restrict__ qbh,
                                        const unsigned short* __restrict__ qbl,
                                        const unsigned short* __restrict__ BtH,
                                        const unsigned short* __restrict__ BtL,
                                        short (*__restrict__ SBh)[64*40],
                                        short (*__restrict__ SBl)[64*40],
                                        float* __restrict__ TPd, int m0) {
  const int tid = threadIdx.x;
  const int w = tid >> 6, lane = tid & 63;
  const int r = lane & 15, qd = lane >> 4;

  f32x4 acc[4][4];   // [h(p-tile)][f(m-tile)]
  #pragma unroll
  for (int h = 0; h < 4; h++)
    #pragma unroll
    for (int f = 0; f < 4; f++) acc[h][f] = (f32x4){0.f,0.f,0.f,0.f};

  int aofs[4];
  #pragma unroll
  for (int h = 0; h < 4; h++) aofs[h] = (w*64 + h*16 + r)*KPAD + KS0*32 + qd*8;

  // B staging: thread t loads row m0+(t>>2), 16B segment (t&3) of the 64B k-chunk
  const int srow = tid >> 2, sseg = tid & 3;
  const size_t gB = (size_t)(m0 + srow)*KPAD + KS0*32 + sseg*8;
  const int swr = srow*40 + sseg*8;      // LDS short offset (stride 40)

  short8 ah[2][4], al[2][4];
  short8 bsh[2], bsl[2];

  // ---- prologue: stage ks=0 into SB[0]; issue ks=1 loads ----
  bsh[0] = *(const short8*)(BtH + gB);
  bsl[0] = *(const short8*)(BtL + gB);
  #pragma unroll
  for (int h = 0; h < 4; h++) {
    ah[0][h] = *(const short8*)(qbh + aofs[h]);
    al[0][h] = *(const short8*)(qbl + aofs[h]);
  }
  *(short8*)&SBh[0][swr] = bsh[0];
  *(short8*)&SBl[0][swr] = bsl[0];
  bsh[1] = *(const short8*)(BtH + gB + 32);
  bsl[1] = *(const short8*)(BtL + gB + 32);
  #pragma unroll
  for (int h = 0; h < 4; h++) {
    ah[1][h] = *(const short8*)(qbh + aofs[h] + 32);
    al[1][h] = *(const short8*)(qbl + aofs[h] + 32);
  }
  __syncthreads();

  #pragma unroll
  for (int ks = 0; ks < NKS; ks++) {
    const int cur = ks & 1, nxt = cur ^ 1;
    // B fragments from LDS (8 x ds_read_b128)
    short8 bfh[4], bfl[4];
    #pragma unroll
    for (int f = 0; f < 4; f++) {
      bfh[f] = *(const short8*)&SBh[cur][(f*16 + r)*40 + qd*8];
      bfl[f] = *(const short8*)&SBl[cur][(f*16 + r)*40 + qd*8];
    }
    #pragma unroll
    for (int f = 0; f < 4; f++)
      #pragma unroll
      for (int h = 0; h < 4; h++) {
        acc[h][f] = __builtin_amdgcn_mfma_f32_16x16x32_bf16(ah[cur][h], bfh[f], acc[h][f], 0, 0, 0);
        acc[h][f] = __builtin_amdgcn_mfma_f32_16x16x32_bf16(ah[cur][h], bfl[f], acc[h][f], 0, 0, 0);
        acc[h][f] = __builtin_amdgcn_mfma_f32_16x16x32_bf16(al[cur][h], bfh[f], acc[h][f], 0, 0, 0);
      }
    if (ks + 1 < NKS) {                    // write staged B(ks+1) -> SB[nxt]
      *(short8*)&SBh[nxt][swr] = bsh[nxt]; // (SB[nxt] readers finished before
      *(short8*)&SBl[nxt][swr] = bsl[nxt]; //  barrier ks-1; safe)
    }
    if (ks + 2 < NKS) {                    // issue loads for ks+2
      const int o = (ks + 2) * 32;
      bsh[cur] = *(const short8*)(BtH + gB + o);
      bsl[cur] = *(const short8*)(BtL + gB + o);
      #pragma unroll
      for (int h = 0; h < 4; h++) {
        ah[cur][h] = *(const short8*)(qbh + aofs[h] + o);
        al[cur][h] = *(const short8*)(qbl + aofs[h] + o);
      }
    }
    __syncthreads();
  }
  // C layout: col = lane&15 (m), row = qd*4 + g (p); skip pad rows p>=200
  #pragma unroll
  for (int h = 0; h < 4; h++)
    #pragma unroll
    for (int f = 0; f < 4; f++)
      #pragma unroll
      for (int g = 0; g < 4; g++) {
        int p = w*64 + h*16 + qd*4 + g;
        if (p < PREG)
          TPd[(size_t)p*TP_STRIDE + m0 + f*16 + r] = acc[h][f][g];
      }
}

__global__ __launch_bounds__(256) void kB(float* __restrict__ ws) {
  __shared__ short SBh[2][64*40];          // 10 KB
  __shared__ short SBl[2][64*40];          // 10 KB
  const unsigned short* qbh = (const unsigned short*)ws + QBH_OFF_U;
  const unsigned short* qbl = (const unsigned short*)ws + QBL_OFF_U;
  const unsigned short* BtH = (const unsigned short*)ws + BTH_OFF_U;
  const unsigned short* BtL = (const unsigned short*)ws + BTL_OFF_U;
  const int m0 = blockIdx.x * 64;
  if (blockIdx.y == 0)
    kb_body<0, 7>(qbh, qbl, BtH, BtL, SBh, SBl, ws + TP_OFF, m0);
  else
    kb_body<7, 6>(qbh, qbl, BtH, BtL, SBh, SBl, ws + TP2_OFF, m0);
}

// ---- kC: skinning + verts + E_D. 1 vert/thread, 8 poses/block
//      (grid 27 x 25): Wp read ONCE per block (round-4 verified: -8 us).
//      G via wave-uniform pointer -> s_loads. ----
__global__ __launch_bounds__(256) void kC(const float* __restrict__ V,
                                          const float* __restrict__ T,
                                          const float* __restrict__ Wp,
                                          const float* __restrict__ ws,
                                          float* __restrict__ out) {
  int p0 = blockIdx.y * 8;
  int n = blockIdx.x*256 + threadIdx.x;
  __shared__ float tmp[4];
  float ed = 0.f;
  if (n < NV) {
    float wv[24]; float sum = 0.f;
    const float4* wp4 = (const float4*)(Wp + n*24);
    #pragma unroll
    for (int i = 0; i < 6; i++) {
      float4 v4 = wp4[i];
      wv[4*i+0] = fmaxf(v4.x, 0.f); wv[4*i+1] = fmaxf(v4.y, 0.f);
      wv[4*i+2] = fmaxf(v4.z, 0.f); wv[4*i+3] = fmaxf(v4.w, 0.f);
      sum += wv[4*i+0]+wv[4*i+1]+wv[4*i+2]+wv[4*i+3];
    }
    float inv = 1.f/(sum + 1e-8f);
    for (int pp = 0; pp < 8; pp++) {
      int p = p0 + pp;
      const float* __restrict__ gp = ws + G_OFF + (size_t)p*288;  // uniform -> s_load
      float M[12];
      #pragma unroll
      for (int i = 0; i < 12; i++) M[i] = 0.f;
      #pragma unroll
      for (int k = 0; k < 24; k++) {
        float wc = wv[k];
        #pragma unroll
        for (int i = 0; i < 12; i++)
          M[i] = fmaf(wc, gp[k*12 + i], M[i]);   // sgpr src0
      }
      #pragma unroll
      for (int i = 0; i < 12; i++) M[i] *= inv;
      size_t tb = (size_t)p*M_TOT + 3*n;
      size_t pb = (size_t)p*TP_STRIDE + 3*n;
      float t0 = ws[TP_OFF + pb + 0] + ws[TP2_OFF + pb + 0] + T[tb + 0];
      float t1 = ws[TP_OFF + pb + 1] + ws[TP2_OFF + pb + 1] + T[tb + 1];
      float t2 = ws[TP_OFF + pb + 2] + ws[TP2_OFF + pb + 2] + T[tb + 2];
      float v0 = M[0]*t0 + M[1]*t1 + M[2]*t2  + M[3];
      float v1 = M[4]*t0 + M[5]*t1 + M[6]*t2  + M[7];
      float v2 = M[8]*t0 + M[9]*t1 + M[10]*t2 + M[11];
      out[1+tb+0] = v0; out[1+tb+1] = v1; out[1+tb+2] = v2;
      float d0 = V[tb+0]-v0, d1 = V[tb+1]-v1, d2 = V[tb+2]-v2;
      ed += d0*d0 + d1*d1 + d2*d2;
    }
  }
  ed = waveReduce(ed);
  int lane = threadIdx.x & 63, w = threadIdx.x >> 6;
  if (lane == 0) tmp[w] = ed;
  __syncthreads();
  if (threadIdx.x == 0)
    ((float*)ws)[EDP_OFF + blockIdx.y*27 + blockIdx.x] = tmp[0]+tmp[1]+tmp[2]+tmp[3];
}

// ---- kF1: parallel partial reductions (25 blocks) ----
__global__ __launch_bounds__(256) void kF1(float* __restrict__ ws) {
  __shared__ float sb[4];
  int b = blockIdx.x, t = threadIdx.x, lane = t & 63, w = t >> 6;
  if (b < 23) {
    float s = 0.f;
    for (int i = t; i < NSTAGE; i += 256) s += ws[EKP_OFF + b*NSTAGE + i];
    s = waveReduce(s);
    if (lane == 0) sb[w] = s;
    __syncthreads();
    if (t == 0) ws[RED_OFF + b] = sb[0]+sb[1]+sb[2]+sb[3];
  } else if (b == 23) {
    float s = 0.f;
    for (int i = t; i < 675; i += 256) s += ws[EDP_OFF + i];
    s = waveReduce(s);
    if (lane == 0) sb[w] = s;
    __syncthreads();
    if (t == 0) ws[RED_OFF + 23] = sb[0]+sb[1]+sb[2]+sb[3];
  } else {
    if (w == 0) {
      float s = (lane < 27) ? ws[WIP_OFF + lane] : 0.f;
      s = waveReduce(s);
      if (lane == 0) ws[RED_OFF + 24] = s;
    } else if (w == 1) {
      float s = (lane < 27) ? ws[EWP_OFF + lane] : 0.f;
      s = waveReduce(s);
      if (lane == 0) ws[RED_OFF + 25] = s;
    } else if (w == 2) {
      float s = (lane < 27) ? ws[EAP_OFF + lane] : 0.f;
      s = waveReduce(s);
      if (lane == 0) ws[RED_OFF + 26] = s;
    }
  }
}

// ---- kF2: final combine ----
__global__ void kF2(const int* __restrict__ epoch, const float* __restrict__ ws,
                    float* __restrict__ out) {
  int t = threadIdx.x;
  float s = (t < 23) ? sqrtf(ws[RED_OFF + t]) : 0.f;
  s = waveReduce(s);
  if (t == 0) {
    float e    = (float)epoch[0];
    float g_wi = 0.1f   * expf(-0.1f  * e);
    float g_w  = 0.002f * expf(-0.008f* e);
    float g_a  = 0.001f * expf(-0.008f* e);
    float g_k  = 0.1f   * expf(-0.008f* e);
    out[0] = ws[RED_OFF+23] + g_wi*ws[RED_OFF+24] + g_w*ws[RED_OFF+25]
           + g_a*ws[RED_OFF+26] + g_k*s;
  }
}

extern "C" void kernel_launch(void* const* d_in, const int* in_sizes, int n_in,
                              void* d_out, int out_size, void* d_ws, size_t ws_size,
                              hipStream_t stream) {
  const float* V     = (const float*)d_in[0];
  const float* T     = (const float*)d_in[1];
  const float* J     = (const float*)d_in[2];
  const float* theta = (const float*)d_in[3];
  const float* Wp    = (const float*)d_in[4];
  const float* Wi    = (const float*)d_in[5];
  const float* A     = (const float*)d_in[6];
  const float* K     = (const float*)d_in[7];
  const float* b2    = (const float*)d_in[8];
  const int*   epoch = (const int*)d_in[9];
  float* out = (float*)d_out;
  float* ws  = (float*)d_ws;
  // needs ~78 MB workspace

  hipLaunchKernelGGL(kPre, dim3(77 + NSTAGE), dim3(256), 0, stream,
                     J, theta, b2, Wp, Wi, A, K, ws);
  hipLaunchKernelGGL(kB,   dim3(NMT64, 2),    dim3(256), 0, stream, ws);
  hipLaunchKernelGGL(kC,   dim3(27, 25),      dim3(256), 0, stream, V, T, Wp, ws, out);
  hipLaunchKernelGGL(kF1,  dim3(25),          dim3(256), 0, stream, ws);
  hipLaunchKernelGGL(kF2,  dim3(1),           dim3(64),  0, stream, epoch, ws, out);
}

// Round 7
// 180.973 us; speedup vs baseline: 1.0127x; 1.0127x over previous
//
#include <hip/hip_runtime.h>
#include <math.h>

// Problem constants
#define KJ 24
#define NV 6890
#define PREG 200
#define M_TOT (NV*3)          // 20670
#define KDIM 391              // 23*17
#define KPAD 416              // 13 chunks of 32
#define TP_STRIDE 20672       // TP row stride (2 pad cols)
#define NMT64 323             // 64-wide m-tiles (kStage AND kB)
#define NSTAGE (NMT64*13)     // 4199 stage blocks

// Workspace layout (float offsets unless _U = ushort offsets). ~78 MB total.
#define EDP_OFF 0               // 675 E_D partials (kC 27 x 25)
#define EKP_OFF 5400            // 23*4199 = 96,577 E_K partials (kStage)
#define WIP_OFF 101984          // 27 E_Wi partials
#define EWP_OFF 102016          // 27 E_W partials
#define EAP_OFF 102048          // 27 E_A partials
#define RED_OFF 102080          // 32 final partials
#define G_OFF   102112          // G' : 200 x 24 x 12
#define TP_OFF  159712          // T_p 256 x 20672 (p-major), K-half 0
#define QBH_OFF_U 10903488      // qm hi bf16, 256 x 416
#define QBL_OFF_U 11009984      // qm lo bf16, 256 x 416
#define BTH_OFF_U 11116480      // Bt hi bf16, 20672 x 416 (m-major)
#define BTL_OFF_U 19716032      // Bt lo bf16, 20672 x 416
#define TP2_OFF 14157792        // T_p partial, K-half 1

typedef __attribute__((ext_vector_type(8))) short short8;
typedef __attribute__((ext_vector_type(4))) float f32x4;
typedef __attribute__((ext_vector_type(4))) unsigned int u32x4;

__constant__ int c_PARENT[24] = {0,0,0,0,1,2,3,4,5,6,7,8,9,9,9,12,13,14,16,17,18,19,20,21};
__constant__ int c_DEPTH[24]  = {0,1,1,1,2,2,2,3,3,3,4,4,4,4,4,5,5,5,6,6,7,7,8,8};
__constant__ int c_LEN[24]    = {4,3,3,3,3,3,3,3,3,2,2,2,4,3,3,2,3,3,3,3,3,3,2,2};
__constant__ int c_NBR[24][4] = {
  {0,1,2,3},{0,1,4,0},{0,2,5,0},{0,3,6,0},{1,4,7,0},{2,5,8,0},{3,6,9,0},{4,7,10,0},
  {5,8,11,0},{6,9,0,0},{7,10,0,0},{8,11,0,0},{12,13,14,15},{12,13,16,0},{12,14,17,0},
  {12,15,0,0},{13,16,18,0},{14,17,19,0},{16,18,20,0},{17,19,21,0},{18,20,22,0},
  {19,21,23,0},{20,22,0,0},{21,23,0,0}};

__device__ __forceinline__ float waveReduce(float v) {
  #pragma unroll
  for (int off = 32; off > 0; off >>= 1) v += __shfl_down(v, off, 64);
  return v;
}
__device__ __forceinline__ unsigned short f2bf(float x) {
  union { float f; unsigned u; } v; v.f = x;
  unsigned r = v.u + 0x7FFFu + ((v.u >> 16) & 1u);
  return (unsigned short)(r >> 16);
}
__device__ __forceinline__ float bf2f(unsigned short h) {
  union { unsigned u; float f; } v; v.u = ((unsigned)h) << 16; return v.f;
}

// ---- kPre: b<50: pose math (4 p/block) -> G' + qm bf16 hi/lo planes
//            b<77: E_Wi/E_W/E_A partials + qm pad-row zeroing
//            else: kStage — Bt[m][k] = bf16-split(K ⊙ reluA) transpose + E_K.
//      NEW: per-block A window staged to LDS (SA[3][24]) — was 1024 scalar
//      global loads/block (4.3M chip-wide TA requests) for ~180B unique data. ----
__global__ __launch_bounds__(256) void kPre(const float* __restrict__ J,
                                            const float* __restrict__ theta,
                                            const float* __restrict__ beta2,
                                            const float* __restrict__ Wp,
                                            const float* __restrict__ Wi,
                                            const float* __restrict__ A,
                                            const float* __restrict__ K,
                                            float* __restrict__ ws) {
  unsigned short* qbh = (unsigned short*)ws + QBH_OFF_U;
  unsigned short* qbl = (unsigned short*)ws + QBL_OFF_U;
  int b = blockIdx.x;
  if (b < 50) {
    __shared__ float Gl[4][24][12];
    __shared__ float Gg[4][24][12];
    __shared__ float q[4][24][4];
    int w = threadIdx.x >> 6, t = threadIdx.x & 63;
    int p = b*4 + w;
    if (t < 24) {
      float x = theta[p*72 + 3*t + 0];
      float y = theta[p*72 + 3*t + 1];
      float z = theta[p*72 + 3*t + 2];
      float n2 = x*x + y*y + z*z;
      float ang = fmaxf(sqrtf(n2), 1e-8f);
      float ia = 1.f/ang;
      float ax = x*ia, ay = y*ia, az = z*ia;
      float c = cosf(ang), s = sinf(ang), C = 1.f - c;
      float jx = J[p*72+3*t], jy = J[p*72+3*t+1], jz = J[p*72+3*t+2];
      float tx = jx, ty = jy, tz = jz;
      if (t > 0) {
        int par = c_PARENT[t];
        tx -= J[p*72+3*par]; ty -= J[p*72+3*par+1]; tz -= J[p*72+3*par+2];
      }
      Gl[w][t][0]=c+C*ax*ax;   Gl[w][t][1]=C*ax*ay-s*az; Gl[w][t][2]=C*ax*az+s*ay; Gl[w][t][3]=tx;
      Gl[w][t][4]=C*ax*ay+s*az;Gl[w][t][5]=c+C*ay*ay;    Gl[w][t][6]=C*ay*az-s*ax; Gl[w][t][7]=ty;
      Gl[w][t][8]=C*ax*az-s*ay;Gl[w][t][9]=C*ay*az+s*ax; Gl[w][t][10]=c+C*az*az;   Gl[w][t][11]=tz;
      float ang2 = sqrtf(fmaxf(n2, 1e-16f));
      float inv2 = 1.f/ang2;
      float s2 = sinf(0.5f*ang2);
      q[w][t][0] = x*inv2*s2; q[w][t][1] = y*inv2*s2; q[w][t][2] = z*inv2*s2;
      q[w][t][3] = cosf(0.5f*ang2) - 1.f;
    }
    __syncthreads();
    for (int lev = 0; lev <= 8; lev++) {
      if (t < 24 && c_DEPTH[t] == lev) {
        if (lev == 0) {
          for (int i2 = 0; i2 < 12; i2++) Gg[w][0][i2] = Gl[w][0][i2];
        } else {
          int par = c_PARENT[t];
          for (int r = 0; r < 3; r++) {
            float g0 = Gg[w][par][r*4+0], g1 = Gg[w][par][r*4+1];
            float g2 = Gg[w][par][r*4+2], g3 = Gg[w][par][r*4+3];
            for (int c2 = 0; c2 < 4; c2++) {
              float v = g0*Gl[w][t][0+c2] + g1*Gl[w][t][4+c2] + g2*Gl[w][t][8+c2];
              if (c2 == 3) v += g3;
              Gg[w][t][r*4+c2] = v;
            }
          }
        }
      }
      __syncthreads();
    }
    if (t < 24) {
      float jx = J[p*72+3*t], jy = J[p*72+3*t+1], jz = J[p*72+3*t+2];
      float* gp = ws + G_OFF + p*288 + t*12;
      #pragma unroll
      for (int r = 0; r < 3; r++) {
        float off = Gg[w][t][r*4+0]*jx + Gg[w][t][r*4+1]*jy + Gg[w][t][r*4+2]*jz;
        Gg[w][t][r*4+3] -= off;
      }
      #pragma unroll
      for (int i2 = 0; i2 < 12; i2++) gp[i2] = Gg[w][t][i2];
    }
    __syncthreads();
    float b2 = beta2[0];
    for (int e = t; e < KDIM; e += 64) {
      int j = e / 17, l = e - 17*j;
      int k = j + 1;
      float val = 0.f;
      if (l < 4*c_LEN[j] + 1) {
        if (l < 16) {
          int sidx = l >> 2, cc = l & 3;
          if (sidx < c_LEN[k]) val = q[w][c_NBR[k][sidx]][cc];
        }
        if (l == 4*c_LEN[k]) val += b2;
      }
      unsigned short hi = f2bf(val);
      unsigned short lo = f2bf(val - bf2f(hi));
      qbh[p*KPAD + e] = hi;
      qbl[p*KPAD + e] = lo;
    }
    for (int e = KDIM + t; e < KPAD; e += 64) {
      qbh[p*KPAD + e] = 0; qbl[p*KPAD + e] = 0;
    }
  } else if (b < 77) {
    int d = b - 50;                        // 0..26
    int t = threadIdx.x;
    int n = d*256 + t;
    float ewi = 0.f, ew = 0.f, ea = 0.f;
    if (n < NV) {
      float wv[24]; float sum = 0.f;
      const float4* wp4 = (const float4*)(Wp + n*24);
      #pragma unroll
      for (int i = 0; i < 6; i++) {
        float4 v4 = wp4[i];
        wv[4*i+0] = fmaxf(v4.x, 0.f); wv[4*i+1] = fmaxf(v4.y, 0.f);
        wv[4*i+2] = fmaxf(v4.z, 0.f); wv[4*i+3] = fmaxf(v4.w, 0.f);
        sum += wv[4*i+0]+wv[4*i+1]+wv[4*i+2]+wv[4*i+3];
      }
      float inv = 1.f/(sum + 1e-8f);
      #pragma unroll
      for (int k = 0; k < 24; k++) {
        float wc = wv[k]*inv;
        ew += fabsf(wc);
        float dd = wc - Wi[n*24+k];
        ewi += dd*dd;
      }
    }
    for (int i = d*256 + t; i < 23*NV; i += 27*256) ea += fabsf(A[i]);
    for (int i = d*256 + t; i < 56*KPAD; i += 27*256) {
      qbh[200*KPAD + i] = 0; qbl[200*KPAD + i] = 0;
    }
    __shared__ float red[3][4];
    int lane = t & 63, wv2 = t >> 6;
    ewi = waveReduce(ewi); ew = waveReduce(ew); ea = waveReduce(ea);
    if (lane == 0) { red[0][wv2] = ewi; red[1][wv2] = ew; red[2][wv2] = ea; }
    __syncthreads();
    if (t == 0) {
      ws[WIP_OFF + d] = red[0][0]+red[0][1]+red[0][2]+red[0][3];
      ws[EWP_OFF + d] = red[1][0]+red[1][1]+red[1][2]+red[1][3];
      ws[EAP_OFF + d] = red[2][0]+red[2][1]+red[2][2]+red[2][3];
    }
  } else {
    // ---------------- kStage: 64m x 32k tile transpose ----------------
    int flat = b - 77;                     // 0..4198
    int bx = flat % NMT64, by = flat / NMT64;
    int m0 = bx*64, kg0 = by*32;
    __shared__ unsigned short Sh[32*66];   // [krow][m], stride 66 (2-way-free)
    __shared__ unsigned short Sl[32*66];
    __shared__ float ek[23];
    __shared__ float SA[3][24];            // relu(A) window: j in [jmin,jmin+2], n in [nb0b,nb0b+23]
    int t = threadIdx.x;
    const int jmin = kg0 / 17, nb0b = m0 / 3;
    if (t < 23) ek[t] = 0.f;
    if (t < 72) {
      int jj = t / 24, nn = t - jj*24;
      int j2 = jmin + jj, n2 = nb0b + nn;
      SA[jj][nn] = (j2 < 23 && n2 < NV) ? fmaxf(A[j2*NV + n2], 0.f) : 0.f;
    }
    __syncthreads();
    int krow = t >> 3, mseg = (t & 7) * 8;
    int kg = kg0 + krow;
    int mm = m0 + mseg;
    float kv[8], wv[8]; float sq = 0.f;
    #pragma unroll
    for (int i = 0; i < 8; i++) { kv[i] = 0.f; wv[i] = 0.f; }
    if (kg < KDIM) {
      const float* kr = K + (size_t)kg*M_TOT + mm;
      if (mm + 7 < M_TOT) {
        float4 a4 = *(const float4*)kr; float4 b4 = *(const float4*)(kr+4);
        kv[0]=a4.x; kv[1]=a4.y; kv[2]=a4.z; kv[3]=a4.w;
        kv[4]=b4.x; kv[5]=b4.y; kv[6]=b4.z; kv[7]=b4.w;
      } else {
        #pragma unroll
        for (int i = 0; i < 8; i++) if (mm+i < M_TOT) kv[i] = kr[i];
      }
      int jj = kg/17 - jmin;
      int nb = mm / 3;
      float av[4];
      #pragma unroll
      for (int i = 0; i < 4; i++)
        av[i] = SA[jj][nb - nb0b + i];     // staged; OOB/relu folded in
      #pragma unroll
      for (int i = 0; i < 8; i++) {
        float a = (mm+i < M_TOT) ? av[(mm+i)/3 - nb] : 0.f;
        wv[i] = kv[i]*a;
        sq = fmaf(kv[i], kv[i], sq);
      }
    }
    #pragma unroll
    for (int c = 0; c < 4; c++) {
      unsigned short h0 = f2bf(wv[2*c]),  h1 = f2bf(wv[2*c+1]);
      unsigned short l0 = f2bf(wv[2*c]   - bf2f(h0));
      unsigned short l1 = f2bf(wv[2*c+1] - bf2f(h1));
      *(unsigned*)&Sh[krow*66 + mseg + 2*c] = (unsigned)h0 | ((unsigned)h1 << 16);
      *(unsigned*)&Sl[krow*66 + mseg + 2*c] = (unsigned)l0 | ((unsigned)l1 << 16);
    }
    sq += __shfl_xor(sq, 1, 64);
    sq += __shfl_xor(sq, 2, 64);
    sq += __shfl_xor(sq, 4, 64);
    if ((t & 7) == 0 && kg < KDIM) atomicAdd(&ek[kg/17], sq);
    __syncthreads();
    int mrow = t >> 2, kq = t & 3;
    unsigned dh[4], dl[4];
    #pragma unroll
    for (int c2 = 0; c2 < 4; c2++) {
      unsigned short s0 = Sh[(kq*8 + 2*c2    )*66 + mrow];
      unsigned short s1 = Sh[(kq*8 + 2*c2 + 1)*66 + mrow];
      dh[c2] = (unsigned)s0 | ((unsigned)s1 << 16);
      unsigned short u0 = Sl[(kq*8 + 2*c2    )*66 + mrow];
      unsigned short u1 = Sl[(kq*8 + 2*c2 + 1)*66 + mrow];
      dl[c2] = (unsigned)u0 | ((unsigned)u1 << 16);
    }
    unsigned short* BtH = (unsigned short*)ws + BTH_OFF_U;
    unsigned short* BtL = (unsigned short*)ws + BTL_OFF_U;
    size_t o = (size_t)(m0 + mrow)*KPAD + kg0 + kq*8;
    *(u32x4*)(BtH + o) = (u32x4){dh[0], dh[1], dh[2], dh[3]};
    *(u32x4*)(BtL + o) = (u32x4){dl[0], dl[1], dl[2], dl[3]};
    if (t < 23) ws[EKP_OFF + t*NSTAGE + flat] = ek[t];
  }
}

// ---- kB: split-bf16 MFMA GEMM, m-tile 64, split-K x2 (grid 323 x 2),
//      256 thr. ROUND-5 EXACT (best measured, A/B vs stride-40 in R6:
//      179.4 vs 183.3): fragment-major LINEAR LDS, slot = f*64 + lane
//      (write: (srow>>4)*64 + sseg*16 + (srow&15) — exact involution). ----
template<int KS0, int NKS>
__device__ __forceinline__ void kb_body(const unsigned short* __restrict__ qbh,
                                        const unsigned short* __restrict__ qbl,
                                        const unsigned short* __restrict__ BtH,
                                        const unsigned short* __restrict__ BtL,
                                        short (*__restrict__ SBh)[64*32],
                                        short (*__restrict__ SBl)[64*32],
                                        float* __restrict__ TPd, int m0) {
  const int tid = threadIdx.x;
  const int w = tid >> 6, lane = tid & 63;
  const int r = lane & 15, qd = lane >> 4;

  f32x4 acc[4][4];   // [h(p-tile)][f(m-tile)]
  #pragma unroll
  for (int h = 0; h < 4; h++)
    #pragma unroll
    for (int f = 0; f < 4; f++) acc[h][f] = (f32x4){0.f,0.f,0.f,0.f};

  int aofs[4];
  #pragma unroll
  for (int h = 0; h < 4; h++) aofs[h] = (w*64 + h*16 + r)*KPAD + KS0*32 + qd*8;

  // B staging: thread t loads row m0+(t>>2), 16B segment (t&3) of the 64B k-chunk
  const int srow = tid >> 2, sseg = tid & 3;
  const size_t gB = (size_t)(m0 + srow)*KPAD + KS0*32 + sseg*8;
  // linear fragment-major LDS slot (16B units): f*64 + qd*16 + r
  const int swr = ((srow >> 4)*64 + sseg*16 + (srow & 15)) * 8;

  short8 ah[2][4], al[2][4];
  short8 bsh[2], bsl[2];

  // ---- prologue: stage ks=0 into SB[0]; issue ks=1 loads ----
  bsh[0] = *(const short8*)(BtH + gB);
  bsl[0] = *(const short8*)(BtL + gB);
  #pragma unroll
  for (int h = 0; h < 4; h++) {
    ah[0][h] = *(const short8*)(qbh + aofs[h]);
    al[0][h] = *(const short8*)(qbl + aofs[h]);
  }
  *(short8*)&SBh[0][swr] = bsh[0];
  *(short8*)&SBl[0][swr] = bsl[0];
  bsh[1] = *(const short8*)(BtH + gB + 32);
  bsl[1] = *(const short8*)(BtL + gB + 32);
  #pragma unroll
  for (int h = 0; h < 4; h++) {
    ah[1][h] = *(const short8*)(qbh + aofs[h] + 32);
    al[1][h] = *(const short8*)(qbl + aofs[h] + 32);
  }
  __syncthreads();

  #pragma unroll
  for (int ks = 0; ks < NKS; ks++) {
    const int cur = ks & 1, nxt = cur ^ 1;
    // B fragments from LDS: lane-linear 1KB reads
    short8 bfh[4], bfl[4];
    #pragma unroll
    for (int f = 0; f < 4; f++) {
      bfh[f] = *(const short8*)&SBh[cur][(f*64 + lane)*8];
      bfl[f] = *(const short8*)&SBl[cur][(f*64 + lane)*8];
    }
    #pragma unroll
    for (int f = 0; f < 4; f++)
      #pragma unroll
      for (int h = 0; h < 4; h++) {
        acc[h][f] = __builtin_amdgcn_mfma_f32_16x16x32_bf16(ah[cur][h], bfh[f], acc[h][f], 0, 0, 0);
        acc[h][f] = __builtin_amdgcn_mfma_f32_16x16x32_bf16(ah[cur][h], bfl[f], acc[h][f], 0, 0, 0);
        acc[h][f] = __builtin_amdgcn_mfma_f32_16x16x32_bf16(al[cur][h], bfh[f], acc[h][f], 0, 0, 0);
      }
    if (ks + 1 < NKS) {                    // write staged B(ks+1) -> SB[nxt]
      *(short8*)&SBh[nxt][swr] = bsh[nxt]; // (SB[nxt] readers finished before
      *(short8*)&SBl[nxt][swr] = bsl[nxt]; //  barrier ks-1; safe)
    }
    if (ks + 2 < NKS) {                    // issue loads for ks+2
      const int o = (ks + 2) * 32;
      bsh[cur] = *(const short8*)(BtH + gB + o);
      bsl[cur] = *(const short8*)(BtL + gB + o);
      #pragma unroll
      for (int h = 0; h < 4; h++) {
        ah[cur][h] = *(const short8*)(qbh + aofs[h] + o);
        al[cur][h] = *(const short8*)(qbl + aofs[h] + o);
      }
    }
    __syncthreads();
  }
  // C layout: col = lane&15 (m), row = qd*4 + g (p); skip pad rows p>=200
  #pragma unroll
  for (int h = 0; h < 4; h++)
    #pragma unroll
    for (int f = 0; f < 4; f++)
      #pragma unroll
      for (int g = 0; g < 4; g++) {
        int p = w*64 + h*16 + qd*4 + g;
        if (p < PREG)
          TPd[(size_t)p*TP_STRIDE + m0 + f*16 + r] = acc[h][f][g];
      }
}

__global__ __launch_bounds__(256) void kB(float* __restrict__ ws) {
  __shared__ short SBh[2][64*32];          // 8 KB (2 x 2048 shorts)
  __shared__ short SBl[2][64*32];          // 8 KB
  const unsigned short* qbh = (const unsigned short*)ws + QBH_OFF_U;
  const unsigned short* qbl = (const unsigned short*)ws + QBL_OFF_U;
  const unsigned short* BtH = (const unsigned short*)ws + BTH_OFF_U;
  const unsigned short* BtL = (const unsigned short*)ws + BTL_OFF_U;
  const int m0 = blockIdx.x * 64;
  if (blockIdx.y == 0)
    kb_body<0, 7>(qbh, qbl, BtH, BtL, SBh, SBl, ws + TP_OFF, m0);
  else
    kb_body<7, 6>(qbh, qbl, BtH, BtL, SBh, SBl, ws + TP2_OFF, m0);
}

// ---- kC: skinning + verts + E_D. 1 vert/thread, 8 poses/block
//      (grid 27 x 25): Wp read ONCE per block (round-4 verified: -8 us).
//      G via wave-uniform pointer -> s_loads. ----
__global__ __launch_bounds__(256) void kC(const float* __restrict__ V,
                                          const float* __restrict__ T,
                                          const float* __restrict__ Wp,
                                          const float* __restrict__ ws,
                                          float* __restrict__ out) {
  int p0 = blockIdx.y * 8;
  int n = blockIdx.x*256 + threadIdx.x;
  __shared__ float tmp[4];
  float ed = 0.f;
  if (n < NV) {
    float wv[24]; float sum = 0.f;
    const float4* wp4 = (const float4*)(Wp + n*24);
    #pragma unroll
    for (int i = 0; i < 6; i++) {
      float4 v4 = wp4[i];
      wv[4*i+0] = fmaxf(v4.x, 0.f); wv[4*i+1] = fmaxf(v4.y, 0.f);
      wv[4*i+2] = fmaxf(v4.z, 0.f); wv[4*i+3] = fmaxf(v4.w, 0.f);
      sum += wv[4*i+0]+wv[4*i+1]+wv[4*i+2]+wv[4*i+3];
    }
    float inv = 1.f/(sum + 1e-8f);
    for (int pp = 0; pp < 8; pp++) {
      int p = p0 + pp;
      const float* __restrict__ gp = ws + G_OFF + (size_t)p*288;  // uniform -> s_load
      float M[12];
      #pragma unroll
      for (int i = 0; i < 12; i++) M[i] = 0.f;
      #pragma unroll
      for (int k = 0; k < 24; k++) {
        float wc = wv[k];
        #pragma unroll
        for (int i = 0; i < 12; i++)
          M[i] = fmaf(wc, gp[k*12 + i], M[i]);   // sgpr src0
      }
      #pragma unroll
      for (int i = 0; i < 12; i++) M[i] *= inv;
      size_t tb = (size_t)p*M_TOT + 3*n;
      size_t pb = (size_t)p*TP_STRIDE + 3*n;
      float t0 = ws[TP_OFF + pb + 0] + ws[TP2_OFF + pb + 0] + T[tb + 0];
      float t1 = ws[TP_OFF + pb + 1] + ws[TP2_OFF + pb + 1] + T[tb + 1];
      float t2 = ws[TP_OFF + pb + 2] + ws[TP2_OFF + pb + 2] + T[tb + 2];
      float v0 = M[0]*t0 + M[1]*t1 + M[2]*t2  + M[3];
      float v1 = M[4]*t0 + M[5]*t1 + M[6]*t2  + M[7];
      float v2 = M[8]*t0 + M[9]*t1 + M[10]*t2 + M[11];
      out[1+tb+0] = v0; out[1+tb+1] = v1; out[1+tb+2] = v2;
      float d0 = V[tb+0]-v0, d1 = V[tb+1]-v1, d2 = V[tb+2]-v2;
      ed += d0*d0 + d1*d1 + d2*d2;
    }
  }
  ed = waveReduce(ed);
  int lane = threadIdx.x & 63, w = threadIdx.x >> 6;
  if (lane == 0) tmp[w] = ed;
  __syncthreads();
  if (threadIdx.x == 0)
    ((float*)ws)[EDP_OFF + blockIdx.y*27 + blockIdx.x] = tmp[0]+tmp[1]+tmp[2]+tmp[3];
}

// ---- kF1: parallel partial reductions (25 blocks) ----
__global__ __launch_bounds__(256) void kF1(float* __restrict__ ws) {
  __shared__ float sb[4];
  int b = blockIdx.x, t = threadIdx.x, lane = t & 63, w = t >> 6;
  if (b < 23) {
    float s = 0.f;
    for (int i = t; i < NSTAGE; i += 256) s += ws[EKP_OFF + b*NSTAGE + i];
    s = waveReduce(s);
    if (lane == 0) sb[w] = s;
    __syncthreads();
    if (t == 0) ws[RED_OFF + b] = sb[0]+sb[1]+sb[2]+sb[3];
  } else if (b == 23) {
    float s = 0.f;
    for (int i = t; i < 675; i += 256) s += ws[EDP_OFF + i];
    s = waveReduce(s);
    if (lane == 0) sb[w] = s;
    __syncthreads();
    if (t == 0) ws[RED_OFF + 23] = sb[0]+sb[1]+sb[2]+sb[3];
  } else {
    if (w == 0) {
      float s = (lane < 27) ? ws[WIP_OFF + lane] : 0.f;
      s = waveReduce(s);
      if (lane == 0) ws[RED_OFF + 24] = s;
    } else if (w == 1) {
      float s = (lane < 27) ? ws[EWP_OFF + lane] : 0.f;
      s = waveReduce(s);
      if (lane == 0) ws[RED_OFF + 25] = s;
    } else if (w == 2) {
      float s = (lane < 27) ? ws[EAP_OFF + lane] : 0.f;
      s = waveReduce(s);
      if (lane == 0) ws[RED_OFF + 26] = s;
    }
  }
}

// ---- kF2: final combine ----
__global__ void kF2(const int* __restrict__ epoch, const float* __restrict__ ws,
                    float* __restrict__ out) {
  int t = threadIdx.x;
  float s = (t < 23) ? sqrtf(ws[RED_OFF + t]) : 0.f;
  s = waveReduce(s);
  if (t == 0) {
    float e    = (float)epoch[0];
    float g_wi = 0.1f   * expf(-0.1f  * e);
    float g_w  = 0.002f * expf(-0.008f* e);
    float g_a  = 0.001f * expf(-0.008f* e);
    float g_k  = 0.1f   * expf(-0.008f* e);
    out[0] = ws[RED_OFF+23] + g_wi*ws[RED_OFF+24] + g_w*ws[RED_OFF+25]
           + g_a*ws[RED_OFF+26] + g_k*s;
  }
}

extern "C" void kernel_launch(void* const* d_in, const int* in_sizes, int n_in,
                              void* d_out, int out_size, void* d_ws, size_t ws_size,
                              hipStream_t stream) {
  const float* V     = (const float*)d_in[0];
  const float* T     = (const float*)d_in[1];
  const float* J     = (const float*)d_in[2];
  const float* theta = (const float*)d_in[3];
  const float* Wp    = (const float*)d_in[4];
  const float* Wi    = (const float*)d_in[5];
  const float* A     = (const float*)d_in[6];
  const float* K     = (const float*)d_in[7];
  const float* b2    = (const float*)d_in[8];
  const int*   epoch = (const int*)d_in[9];
  float* out = (float*)d_out;
  float* ws  = (float*)d_ws;
  // needs ~78 MB workspace

  hipLaunchKernelGGL(kPre, dim3(77 + NSTAGE), dim3(256), 0, stream,
                     J, theta, b2, Wp, Wi, A, K, ws);
  hipLaunchKernelGGL(kB,   dim3(NMT64, 2),    dim3(256), 0, stream, ws);
  hipLaunchKernelGGL(kC,   dim3(27, 25),      dim3(256), 0, stream, V, T, Wp, ws, out);
  hipLaunchKernelGGL(kF1,  dim3(25),          dim3(256), 0, stream, ws);
  hipLaunchKernelGGL(kF2,  dim3(1),           dim3(64),  0, stream, epoch, ws, out);
}

// Round 8
// 174.849 us; speedup vs baseline: 1.0482x; 1.0350x over previous
//
#include <hip/hip_runtime.h>
#include <math.h>

// Problem constants
#define KJ 24
#define NV 6890
#define PREG 200
#define M_TOT (NV*3)          // 20670
#define KDIM 391              // 23*17
#define KPAD 416              // 13 chunks of 32
#define TP_STRIDE 20672       // TP row stride (2 pad cols)
#define NMT64 323             // 64-wide m-tiles (kB)
#define NKB (NMT64*2)         // 646 kB blocks (m-tile x K-half) -> E_K partials

// Workspace layout (float offsets unless _U = ushort offsets). ~78 MB total.
#define EDP_OFF 0               // 675 E_D partials (kC 27 x 25)
#define EKP_OFF 5400            // 23*646 E_K partials (kB, fused)
#define WIP_OFF 101984          // 27 E_Wi partials
#define EWP_OFF 102016          // 27 E_W partials
#define EAP_OFF 102048          // 27 E_A partials
#define RED_OFF 102080          // 32 final partials
#define G_OFF   102112          // G' : 200 x 24 x 12
#define TP_OFF  159712          // T_p 256 x 20672 (p-major), K-half 0
#define QBH_OFF_U 10903488      // qm hi bf16, 256 x 416
#define QBL_OFF_U 11009984      // qm lo bf16, 256 x 416
#define TP2_OFF 14157792        // T_p partial, K-half 1

typedef __attribute__((ext_vector_type(8))) short short8;
typedef __attribute__((ext_vector_type(4))) float f32x4;
typedef __attribute__((ext_vector_type(4))) unsigned int u32x4;

__constant__ int c_PARENT[24] = {0,0,0,0,1,2,3,4,5,6,7,8,9,9,9,12,13,14,16,17,18,19,20,21};
__constant__ int c_DEPTH[24]  = {0,1,1,1,2,2,2,3,3,3,4,4,4,4,4,5,5,5,6,6,7,7,8,8};
__constant__ int c_LEN[24]    = {4,3,3,3,3,3,3,3,3,2,2,2,4,3,3,2,3,3,3,3,3,3,2,2};
__constant__ int c_NBR[24][4] = {
  {0,1,2,3},{0,1,4,0},{0,2,5,0},{0,3,6,0},{1,4,7,0},{2,5,8,0},{3,6,9,0},{4,7,10,0},
  {5,8,11,0},{6,9,0,0},{7,10,0,0},{8,11,0,0},{12,13,14,15},{12,13,16,0},{12,14,17,0},
  {12,15,0,0},{13,16,18,0},{14,17,19,0},{16,18,20,0},{17,19,21,0},{18,20,22,0},
  {19,21,23,0},{20,22,0,0},{21,23,0,0}};

__device__ __forceinline__ float waveReduce(float v) {
  #pragma unroll
  for (int off = 32; off > 0; off >>= 1) v += __shfl_down(v, off, 64);
  return v;
}
__device__ __forceinline__ unsigned short f2bf(float x) {
  union { float f; unsigned u; } v; v.f = x;
  unsigned r = v.u + 0x7FFFu + ((v.u >> 16) & 1u);
  return (unsigned short)(r >> 16);
}
__device__ __forceinline__ float bf2f(unsigned short h) {
  union { unsigned u; float f; } v; v.u = ((unsigned)h) << 16; return v.f;
}

// ---- kPre (77 blocks): b<50: pose math (4 p/block) -> G' + qm bf16 hi/lo
//      planes; b<77: E_Wi/E_W/E_A partials + qm pad-row zeroing.
//      (kStage DELETED: Bt transpose fused into kB — Bt had zero cross-block
//      reuse, so its 68 MB write+read round-trip was pure waste.) ----
__global__ __launch_bounds__(256) void kPre(const float* __restrict__ J,
                                            const float* __restrict__ theta,
                                            const float* __restrict__ beta2,
                                            const float* __restrict__ Wp,
                                            const float* __restrict__ Wi,
                                            const float* __restrict__ A,
                                            float* __restrict__ ws) {
  unsigned short* qbh = (unsigned short*)ws + QBH_OFF_U;
  unsigned short* qbl = (unsigned short*)ws + QBL_OFF_U;
  int b = blockIdx.x;
  if (b < 50) {
    __shared__ float Gl[4][24][12];
    __shared__ float Gg[4][24][12];
    __shared__ float q[4][24][4];
    int w = threadIdx.x >> 6, t = threadIdx.x & 63;
    int p = b*4 + w;
    if (t < 24) {
      float x = theta[p*72 + 3*t + 0];
      float y = theta[p*72 + 3*t + 1];
      float z = theta[p*72 + 3*t + 2];
      float n2 = x*x + y*y + z*z;
      float ang = fmaxf(sqrtf(n2), 1e-8f);
      float ia = 1.f/ang;
      float ax = x*ia, ay = y*ia, az = z*ia;
      float c = cosf(ang), s = sinf(ang), C = 1.f - c;
      float jx = J[p*72+3*t], jy = J[p*72+3*t+1], jz = J[p*72+3*t+2];
      float tx = jx, ty = jy, tz = jz;
      if (t > 0) {
        int par = c_PARENT[t];
        tx -= J[p*72+3*par]; ty -= J[p*72+3*par+1]; tz -= J[p*72+3*par+2];
      }
      Gl[w][t][0]=c+C*ax*ax;   Gl[w][t][1]=C*ax*ay-s*az; Gl[w][t][2]=C*ax*az+s*ay; Gl[w][t][3]=tx;
      Gl[w][t][4]=C*ax*ay+s*az;Gl[w][t][5]=c+C*ay*ay;    Gl[w][t][6]=C*ay*az-s*ax; Gl[w][t][7]=ty;
      Gl[w][t][8]=C*ax*az-s*ay;Gl[w][t][9]=C*ay*az+s*ax; Gl[w][t][10]=c+C*az*az;   Gl[w][t][11]=tz;
      float ang2 = sqrtf(fmaxf(n2, 1e-16f));
      float inv2 = 1.f/ang2;
      float s2 = sinf(0.5f*ang2);
      q[w][t][0] = x*inv2*s2; q[w][t][1] = y*inv2*s2; q[w][t][2] = z*inv2*s2;
      q[w][t][3] = cosf(0.5f*ang2) - 1.f;
    }
    __syncthreads();
    for (int lev = 0; lev <= 8; lev++) {
      if (t < 24 && c_DEPTH[t] == lev) {
        if (lev == 0) {
          for (int i2 = 0; i2 < 12; i2++) Gg[w][0][i2] = Gl[w][0][i2];
        } else {
          int par = c_PARENT[t];
          for (int r = 0; r < 3; r++) {
            float g0 = Gg[w][par][r*4+0], g1 = Gg[w][par][r*4+1];
            float g2 = Gg[w][par][r*4+2], g3 = Gg[w][par][r*4+3];
            for (int c2 = 0; c2 < 4; c2++) {
              float v = g0*Gl[w][t][0+c2] + g1*Gl[w][t][4+c2] + g2*Gl[w][t][8+c2];
              if (c2 == 3) v += g3;
              Gg[w][t][r*4+c2] = v;
            }
          }
        }
      }
      __syncthreads();
    }
    if (t < 24) {
      float jx = J[p*72+3*t], jy = J[p*72+3*t+1], jz = J[p*72+3*t+2];
      float* gp = ws + G_OFF + p*288 + t*12;
      #pragma unroll
      for (int r = 0; r < 3; r++) {
        float off = Gg[w][t][r*4+0]*jx + Gg[w][t][r*4+1]*jy + Gg[w][t][r*4+2]*jz;
        Gg[w][t][r*4+3] -= off;
      }
      #pragma unroll
      for (int i2 = 0; i2 < 12; i2++) gp[i2] = Gg[w][t][i2];
    }
    __syncthreads();
    float b2 = beta2[0];
    for (int e = t; e < KDIM; e += 64) {
      int j = e / 17, l = e - 17*j;
      int k = j + 1;
      float val = 0.f;
      if (l < 4*c_LEN[j] + 1) {
        if (l < 16) {
          int sidx = l >> 2, cc = l & 3;
          if (sidx < c_LEN[k]) val = q[w][c_NBR[k][sidx]][cc];
        }
        if (l == 4*c_LEN[k]) val += b2;
      }
      unsigned short hi = f2bf(val);
      unsigned short lo = f2bf(val - bf2f(hi));
      qbh[p*KPAD + e] = hi;
      qbl[p*KPAD + e] = lo;
    }
    for (int e = KDIM + t; e < KPAD; e += 64) {
      qbh[p*KPAD + e] = 0; qbl[p*KPAD + e] = 0;
    }
  } else {
    int d = b - 50;                        // 0..26
    int t = threadIdx.x;
    int n = d*256 + t;
    float ewi = 0.f, ew = 0.f, ea = 0.f;
    if (n < NV) {
      float wv[24]; float sum = 0.f;
      const float4* wp4 = (const float4*)(Wp + n*24);
      #pragma unroll
      for (int i = 0; i < 6; i++) {
        float4 v4 = wp4[i];
        wv[4*i+0] = fmaxf(v4.x, 0.f); wv[4*i+1] = fmaxf(v4.y, 0.f);
        wv[4*i+2] = fmaxf(v4.z, 0.f); wv[4*i+3] = fmaxf(v4.w, 0.f);
        sum += wv[4*i+0]+wv[4*i+1]+wv[4*i+2]+wv[4*i+3];
      }
      float inv = 1.f/(sum + 1e-8f);
      #pragma unroll
      for (int k = 0; k < 24; k++) {
        float wc = wv[k]*inv;
        ew += fabsf(wc);
        float dd = wc - Wi[n*24+k];
        ewi += dd*dd;
      }
    }
    for (int i = d*256 + t; i < 23*NV; i += 27*256) ea += fabsf(A[i]);
    for (int i = d*256 + t; i < 56*KPAD; i += 27*256) {
      qbh[200*KPAD + i] = 0; qbl[200*KPAD + i] = 0;
    }
    __shared__ float red[3][4];
    int lane = t & 63, wv2 = t >> 6;
    ewi = waveReduce(ewi); ew = waveReduce(ew); ea = waveReduce(ea);
    if (lane == 0) { red[0][wv2] = ewi; red[1][wv2] = ew; red[2][wv2] = ea; }
    __syncthreads();
    if (t == 0) {
      ws[WIP_OFF + d] = red[0][0]+red[0][1]+red[0][2]+red[0][3];
      ws[EWP_OFF + d] = red[1][0]+red[1][1]+red[1][2]+red[1][3];
      ws[EAP_OFF + d] = red[2][0]+red[2][1]+red[2][2]+red[2][3];
    }
  }
}

// ---- kB: FUSED transpose + split-bf16 MFMA GEMM. m-tile 64, split-K x2
//      (grid 323 x 2), 256 thr. Per K-step: load K slice direct (m-contig,
//      vectorized) -> xreluA -> f32 stage Sk[32][66] (b64 writes, <=2-way)
//      -> barrier -> column-read (b32, <=2-way) + bf16-split -> SB frags
//      (R5's measured-best linear layout) -> barrier -> MFMA.
//      Also computes E_K partials (was kStage's job). K-loads issued BEFORE
//      the MFMA cluster, Sk writes after (T14 issue-early/write-late). ----
template<int KS0, int NKS, int JMIN>
__device__ __forceinline__ void kb_body(const float* __restrict__ A,
                                        const float* __restrict__ K,
                                        const unsigned short* __restrict__ qbh,
                                        const unsigned short* __restrict__ qbl,
                                        float* __restrict__ Sk,
                                        short (*__restrict__ SBh)[64*32],
                                        short (*__restrict__ SBl)[64*32],
                                        float (*__restrict__ SA)[24],
                                        float* __restrict__ ek,
                                        float* __restrict__ ws,
                                        float* __restrict__ TPd,
                                        int m0, int flat) {
  const int tid = threadIdx.x;
  const int w = tid >> 6, lane = tid & 63;
  const int r = lane & 15, qd = lane >> 4;
  const int krow = tid >> 3, mseg = (tid & 7) * 8;
  const int mm = m0 + mseg;
  const int nb0 = m0 / 3;
  const int mrow2 = tid >> 2, kq2 = tid & 3;   // phase-2 mapping
  const int swr = ((mrow2 >> 4)*64 + kq2*16 + (mrow2 & 15)) * 8;

  // ---- init: ek zero + SA window (relu(A), j in [JMIN,JMIN+13], n window 24)
  if (tid < 23) ek[tid] = 0.f;
  for (int i = tid; i < 14*24; i += 256) {
    int jj = i / 24, nn = i - jj*24;
    int j2 = JMIN + jj, n2 = nb0 + nn;
    ((float*)SA)[i] = (j2 < 23 && n2 < NV) ? fmaxf(A[j2*NV + n2], 0.f) : 0.f;
  }

  f32x4 acc[4][4];
  #pragma unroll
  for (int h = 0; h < 4; h++)
    #pragma unroll
    for (int f = 0; f < 4; f++) acc[h][f] = (f32x4){0.f,0.f,0.f,0.f};

  int aofs[4];
  #pragma unroll
  for (int h = 0; h < 4; h++) aofs[h] = (w*64 + h*16 + r)*KPAD + KS0*32 + qd*8;

  short8 ah[2][4], al[2][4];
  float kv[8];

  // ---- load K(ks) into kv (guarded) ----
  auto loadK = [&](int ks) {
    int kg = (KS0 + ks)*32 + krow;
    #pragma unroll
    for (int i = 0; i < 8; i++) kv[i] = 0.f;
    if (kg < KDIM) {
      const float* kr = K + (size_t)kg*M_TOT + mm;
      if (mm + 7 < M_TOT) {
        float4 a4 = *(const float4*)kr; float4 b4 = *(const float4*)(kr+4);
        kv[0]=a4.x; kv[1]=a4.y; kv[2]=a4.z; kv[3]=a4.w;
        kv[4]=b4.x; kv[5]=b4.y; kv[6]=b4.z; kv[7]=b4.w;
      } else {
        #pragma unroll
        for (int i = 0; i < 8; i++) if (mm+i < M_TOT) kv[i] = kr[i];
      }
    }
  };
  // ---- xA, E_K partial, stage to Sk ----
  auto stageK = [&](int ks) {
    int kg = (KS0 + ks)*32 + krow;
    float wv[8]; float sq = 0.f;
    #pragma unroll
    for (int i = 0; i < 8; i++) wv[i] = 0.f;
    if (kg < KDIM) {
      int jj = kg/17 - JMIN;
      int nb = mm / 3;
      float av[4];
      #pragma unroll
      for (int i = 0; i < 4; i++) av[i] = SA[jj][nb - nb0 + i];
      #pragma unroll
      for (int i = 0; i < 8; i++) {
        float a = (mm+i < M_TOT) ? av[(mm+i)/3 - nb] : 0.f;
        wv[i] = kv[i]*a;
        sq = fmaf(kv[i], kv[i], sq);
      }
    }
    #pragma unroll
    for (int c = 0; c < 4; c++)
      *(float2*)&Sk[krow*66 + mseg + 2*c] = make_float2(wv[2*c], wv[2*c+1]);
    sq += __shfl_xor(sq, 1, 64);
    sq += __shfl_xor(sq, 2, 64);
    sq += __shfl_xor(sq, 4, 64);
    if ((tid & 7) == 0 && kg < KDIM) atomicAdd(&ek[kg/17], sq);
  };
  // ---- transpose-read Sk -> bf16-split -> SB[buf] frags ----
  auto xpose = [&](int buf) {
    float vv[8];
    #pragma unroll
    for (int j = 0; j < 8; j++) vv[j] = Sk[(kq2*8 + j)*66 + mrow2];
    unsigned dh[4], dl[4];
    #pragma unroll
    for (int c = 0; c < 4; c++) {
      unsigned short h0 = f2bf(vv[2*c]),   h1 = f2bf(vv[2*c+1]);
      unsigned short l0 = f2bf(vv[2*c]   - bf2f(h0));
      unsigned short l1 = f2bf(vv[2*c+1] - bf2f(h1));
      dh[c] = (unsigned)h0 | ((unsigned)h1 << 16);
      dl[c] = (unsigned)l0 | ((unsigned)l1 << 16);
    }
    *(u32x4*)&SBh[buf][swr] = (u32x4){dh[0], dh[1], dh[2], dh[3]};
    *(u32x4*)&SBl[buf][swr] = (u32x4){dl[0], dl[1], dl[2], dl[3]};
  };

  // ---- prologue: Sk <- K(0); SB[0] <- T(Sk); prefetch qm frags 0,1 ----
  loadK(0);
  #pragma unroll
  for (int h = 0; h < 4; h++) {
    ah[0][h] = *(const short8*)(qbh + aofs[h]);
    al[0][h] = *(const short8*)(qbl + aofs[h]);
  }
  stageK(0);
  __syncthreads();
  xpose(0);
  #pragma unroll
  for (int h = 0; h < 4; h++) {
    ah[1][h] = *(const short8*)(qbh + aofs[h] + 32);
    al[1][h] = *(const short8*)(qbl + aofs[h] + 32);
  }
  __syncthreads();

  #pragma unroll
  for (int ks = 0; ks < NKS; ks++) {
    const int cur = ks & 1, nxt = cur ^ 1;
    if (ks + 1 < NKS) loadK(ks + 1);       // issue global loads early
    short8 bfh[4], bfl[4];
    #pragma unroll
    for (int f = 0; f < 4; f++) {
      bfh[f] = *(const short8*)&SBh[cur][(f*64 + lane)*8];
      bfl[f] = *(const short8*)&SBl[cur][(f*64 + lane)*8];
    }
    #pragma unroll
    for (int f = 0; f < 4; f++)
      #pragma unroll
      for (int h = 0; h < 4; h++) {
        acc[h][f] = __builtin_amdgcn_mfma_f32_16x16x32_bf16(ah[cur][h], bfh[f], acc[h][f], 0, 0, 0);
        acc[h][f] = __builtin_amdgcn_mfma_f32_16x16x32_bf16(ah[cur][h], bfl[f], acc[h][f], 0, 0, 0);
        acc[h][f] = __builtin_amdgcn_mfma_f32_16x16x32_bf16(al[cur][h], bfh[f], acc[h][f], 0, 0, 0);
      }
    if (ks + 1 < NKS) stageK(ks + 1);      // write-late (Sk free since last bar)
    if (ks + 2 < NKS) {                    // qm frag prefetch for ks+2
      const int o = (ks + 2) * 32;
      #pragma unroll
      for (int h = 0; h < 4; h++) {
        ah[cur][h] = *(const short8*)(qbh + aofs[h] + o);
        al[cur][h] = *(const short8*)(qbl + aofs[h] + o);
      }
    }
    __syncthreads();
    if (ks + 1 < NKS) xpose(nxt);          // SB[nxt] free since last bar
    __syncthreads();
  }

  // ---- E_K partial store + C write ----
  if (tid < 23) ws[EKP_OFF + tid*NKB + flat] = ek[tid];
  #pragma unroll
  for (int h = 0; h < 4; h++)
    #pragma unroll
    for (int f = 0; f < 4; f++)
      #pragma unroll
      for (int g = 0; g < 4; g++) {
        int p = w*64 + h*16 + qd*4 + g;
        if (p < PREG)
          TPd[(size_t)p*TP_STRIDE + m0 + f*16 + r] = acc[h][f][g];
      }
}

__global__ __launch_bounds__(256) void kB(const float* __restrict__ A,
                                          const float* __restrict__ K,
                                          float* __restrict__ ws) {
  __shared__ float Sk[32*66];              // 8448 B f32 staging
  __shared__ short SBh[2][64*32];          // 8 KB
  __shared__ short SBl[2][64*32];          // 8 KB
  __shared__ float SA[14][24];             // relu(A) window
  __shared__ float ek[23];
  const unsigned short* qbh = (const unsigned short*)ws + QBH_OFF_U;
  const unsigned short* qbl = (const unsigned short*)ws + QBL_OFF_U;
  const int m0 = blockIdx.x * 64;
  const int flat = blockIdx.x + blockIdx.y * NMT64;
  if (blockIdx.y == 0)
    kb_body<0, 7, 0>(A, K, qbh, qbl, Sk, SBh, SBl, SA, ek, ws, ws + TP_OFF,  m0, flat);
  else
    kb_body<7, 6, 13>(A, K, qbh, qbl, Sk, SBh, SBl, SA, ek, ws, ws + TP2_OFF, m0, flat);
}

// ---- kC: skinning + verts + E_D. 1 vert/thread, 8 poses/block
//      (grid 27 x 25): Wp read ONCE per block (round-4 verified: -8 us).
//      G via wave-uniform pointer -> s_loads. ----
__global__ __launch_bounds__(256) void kC(const float* __restrict__ V,
                                          const float* __restrict__ T,
                                          const float* __restrict__ Wp,
                                          const float* __restrict__ ws,
                                          float* __restrict__ out) {
  int p0 = blockIdx.y * 8;
  int n = blockIdx.x*256 + threadIdx.x;
  __shared__ float tmp[4];
  float ed = 0.f;
  if (n < NV) {
    float wv[24]; float sum = 0.f;
    const float4* wp4 = (const float4*)(Wp + n*24);
    #pragma unroll
    for (int i = 0; i < 6; i++) {
      float4 v4 = wp4[i];
      wv[4*i+0] = fmaxf(v4.x, 0.f); wv[4*i+1] = fmaxf(v4.y, 0.f);
      wv[4*i+2] = fmaxf(v4.z, 0.f); wv[4*i+3] = fmaxf(v4.w, 0.f);
      sum += wv[4*i+0]+wv[4*i+1]+wv[4*i+2]+wv[4*i+3];
    }
    float inv = 1.f/(sum + 1e-8f);
    for (int pp = 0; pp < 8; pp++) {
      int p = p0 + pp;
      const float* __restrict__ gp = ws + G_OFF + (size_t)p*288;  // uniform -> s_load
      float M[12];
      #pragma unroll
      for (int i = 0; i < 12; i++) M[i] = 0.f;
      #pragma unroll
      for (int k = 0; k < 24; k++) {
        float wc = wv[k];
        #pragma unroll
        for (int i = 0; i < 12; i++)
          M[i] = fmaf(wc, gp[k*12 + i], M[i]);   // sgpr src0
      }
      #pragma unroll
      for (int i = 0; i < 12; i++) M[i] *= inv;
      size_t tb = (size_t)p*M_TOT + 3*n;
      size_t pb = (size_t)p*TP_STRIDE + 3*n;
      float t0 = ws[TP_OFF + pb + 0] + ws[TP2_OFF + pb + 0] + T[tb + 0];
      float t1 = ws[TP_OFF + pb + 1] + ws[TP2_OFF + pb + 1] + T[tb + 1];
      float t2 = ws[TP_OFF + pb + 2] + ws[TP2_OFF + pb + 2] + T[tb + 2];
      float v0 = M[0]*t0 + M[1]*t1 + M[2]*t2  + M[3];
      float v1 = M[4]*t0 + M[5]*t1 + M[6]*t2  + M[7];
      float v2 = M[8]*t0 + M[9]*t1 + M[10]*t2 + M[11];
      out[1+tb+0] = v0; out[1+tb+1] = v1; out[1+tb+2] = v2;
      float d0 = V[tb+0]-v0, d1 = V[tb+1]-v1, d2 = V[tb+2]-v2;
      ed += d0*d0 + d1*d1 + d2*d2;
    }
  }
  ed = waveReduce(ed);
  int lane = threadIdx.x & 63, w = threadIdx.x >> 6;
  if (lane == 0) tmp[w] = ed;
  __syncthreads();
  if (threadIdx.x == 0)
    ((float*)ws)[EDP_OFF + blockIdx.y*27 + blockIdx.x] = tmp[0]+tmp[1]+tmp[2]+tmp[3];
}

// ---- kF1: parallel partial reductions (25 blocks) ----
__global__ __launch_bounds__(256) void kF1(float* __restrict__ ws) {
  __shared__ float sb[4];
  int b = blockIdx.x, t = threadIdx.x, lane = t & 63, w = t >> 6;
  if (b < 23) {
    float s = 0.f;
    for (int i = t; i < NKB; i += 256) s += ws[EKP_OFF + b*NKB + i];
    s = waveReduce(s);
    if (lane == 0) sb[w] = s;
    __syncthreads();
    if (t == 0) ws[RED_OFF + b] = sb[0]+sb[1]+sb[2]+sb[3];
  } else if (b == 23) {
    float s = 0.f;
    for (int i = t; i < 675; i += 256) s += ws[EDP_OFF + i];
    s = waveReduce(s);
    if (lane == 0) sb[w] = s;
    __syncthreads();
    if (t == 0) ws[RED_OFF + 23] = sb[0]+sb[1]+sb[2]+sb[3];
  } else {
    if (w == 0) {
      float s = (lane < 27) ? ws[WIP_OFF + lane] : 0.f;
      s = waveReduce(s);
      if (lane == 0) ws[RED_OFF + 24] = s;
    } else if (w == 1) {
      float s = (lane < 27) ? ws[EWP_OFF + lane] : 0.f;
      s = waveReduce(s);
      if (lane == 0) ws[RED_OFF + 25] = s;
    } else if (w == 2) {
      float s = (lane < 27) ? ws[EAP_OFF + lane] : 0.f;
      s = waveReduce(s);
      if (lane == 0) ws[RED_OFF + 26] = s;
    }
  }
}

// ---- kF2: final combine ----
__global__ void kF2(const int* __restrict__ epoch, const float* __restrict__ ws,
                    float* __restrict__ out) {
  int t = threadIdx.x;
  float s = (t < 23) ? sqrtf(ws[RED_OFF + t]) : 0.f;
  s = waveReduce(s);
  if (t == 0) {
    float e    = (float)epoch[0];
    float g_wi = 0.1f   * expf(-0.1f  * e);
    float g_w  = 0.002f * expf(-0.008f* e);
    float g_a  = 0.001f * expf(-0.008f* e);
    float g_k  = 0.1f   * expf(-0.008f* e);
    out[0] = ws[RED_OFF+23] + g_wi*ws[RED_OFF+24] + g_w*ws[RED_OFF+25]
           + g_a*ws[RED_OFF+26] + g_k*s;
  }
}

extern "C" void kernel_launch(void* const* d_in, const int* in_sizes, int n_in,
                              void* d_out, int out_size, void* d_ws, size_t ws_size,
                              hipStream_t stream) {
  const float* V     = (const float*)d_in[0];
  const float* T     = (const float*)d_in[1];
  const float* J     = (const float*)d_in[2];
  const float* theta = (const float*)d_in[3];
  const float* Wp    = (const float*)d_in[4];
  const float* Wi    = (const float*)d_in[5];
  const float* A     = (const float*)d_in[6];
  const float* K     = (const float*)d_in[7];
  const float* b2    = (const float*)d_in[8];
  const int*   epoch = (const int*)d_in[9];
  float* out = (float*)d_out;
  float* ws  = (float*)d_ws;
  // needs ~78 MB workspace

  hipLaunchKernelGGL(kPre, dim3(77),        dim3(256), 0, stream,
                     J, theta, b2, Wp, Wi, A, ws);
  hipLaunchKernelGGL(kB,   dim3(NMT64, 2),  dim3(256), 0, stream, A, K, ws);
  hipLaunchKernelGGL(kC,   dim3(27, 25),    dim3(256), 0, stream, V, T, Wp, ws, out);
  hipLaunchKernelGGL(kF1,  dim3(25),        dim3(256), 0, stream, ws);
  hipLaunchKernelGGL(kF2,  dim3(1),         dim3(64),  0, stream, epoch, ws, out);
}